// Round 7
// baseline (354.127 us; speedup 1.0000x reference)
//
#include <hip/hip_runtime.h>
#include <stdint.h>

// PointNet EdgeConv, 2 layers. Round 7.
// R1: scatter atomics bound (1.6 GB memory-side writes).      4209 us
// R2: gather-per-node spilled (VGPR 256, 9.6 GB scratch).    13742 us
// R3: sorted CSR + block-segmented max in LDS.                 646 us
// R4: scalar-pipe weights, no LDS weights, atomic-free sort.   378 us
// R5: packed v_pk_fma_f32 (g-inner order).                     337 us
// R6: bf16 LDS + launch-bounds squeeze. REGRESSED.             345 us
// R7: ALGEBRAIC: Linear1 is affine => hidden_e = relu(U[src]-V[dst]) with
//     per-node U,V precomputes. Per-edge MLP1 eliminated (both layers now
//     identical kernels). Revert bf16 LDS -> fp32 [BS][33] + ds_write_b128.

#define BS 256

typedef float v2f __attribute__((ext_vector_type(2)));

__device__ __forceinline__ unsigned ordenc(float f) {
    unsigned u = __float_as_uint(f);
    return (u & 0x80000000u) ? ~u : (u | 0x80000000u);
}
__device__ __forceinline__ float orddec(unsigned o) {
    unsigned u = (o & 0x80000000u) ? (o ^ 0x80000000u) : ~o;
    return __uint_as_float(u);
}
#define ORD_NEG_INF 0x007FFFFFu  // ordenc(-inf)

// ---------------- utility kernels ----------------

__global__ __launch_bounds__(BS) void init_kernel(int* __restrict__ cnt, int N,
                                                  unsigned* __restrict__ a,
                                                  unsigned* __restrict__ b, int n32) {
    int i = blockIdx.x * BS + threadIdx.x;
    if (i < N) cnt[i] = 0;
    if (i < n32) {
        a[i] = ORD_NEG_INF;
        b[i] = ORD_NEG_INF;
    }
}

__global__ __launch_bounds__(BS) void finalize_kernel(unsigned* __restrict__ buf, int n) {
    int i = blockIdx.x * BS + threadIdx.x;
    if (i < n) {
        float v = orddec(buf[i]);
        reinterpret_cast<float*>(buf)[i] = fmaxf(v, 0.0f);
    }
}

// ---------------- counting sort (CSR build) ----------------

__global__ __launch_bounds__(BS) void hist_rank_kernel(const int* __restrict__ ei, int E,
                                                       int* __restrict__ cnt,
                                                       int* __restrict__ rank) {
    int e = blockIdx.x * BS + threadIdx.x;
    if (e < E) rank[e] = atomicAdd(&cnt[ei[E + e]], 1);
}

__global__ __launch_bounds__(BS) void bsum_kernel(const int* __restrict__ cnt, int n,
                                                  int* __restrict__ bsum) {
    __shared__ int s[BS];
    int t = threadIdx.x;
    int i = blockIdx.x * BS + t;
    s[t] = (i < n) ? cnt[i] : 0;
    __syncthreads();
    for (int st = BS / 2; st > 0; st >>= 1) {
        if (t < st) s[t] += s[t + st];
        __syncthreads();
    }
    if (t == 0) bsum[blockIdx.x] = s[0];
}

__global__ __launch_bounds__(512) void bscan_kernel(const int* __restrict__ bsum, int nb,
                                                    int* __restrict__ bpre) {
    __shared__ int s[512];
    int t = threadIdx.x;
    int v = (t < nb) ? bsum[t] : 0;
    s[t] = v;
    __syncthreads();
    for (int off = 1; off < 512; off <<= 1) {
        int add = (t >= off) ? s[t - off] : 0;
        __syncthreads();
        s[t] += add;
        __syncthreads();
    }
    if (t < nb) bpre[t] = s[t] - v;  // exclusive
}

__global__ __launch_bounds__(BS) void scan_kernel(const int* __restrict__ cnt, int n,
                                                  const int* __restrict__ bpre,
                                                  int* __restrict__ row_ptr) {
    __shared__ int s[BS];
    int t = threadIdx.x;
    int i = blockIdx.x * BS + t;
    int v = (i < n) ? cnt[i] : 0;
    s[t] = v;
    __syncthreads();
    for (int off = 1; off < BS; off <<= 1) {
        int add = (t >= off) ? s[t - off] : 0;
        __syncthreads();
        s[t] += add;
        __syncthreads();
    }
    if (i < n) row_ptr[i] = bpre[blockIdx.x] + s[t] - v;
}

__global__ __launch_bounds__(BS) void scatter_kernel(const int* __restrict__ ei, int E,
                                                     const int* __restrict__ row_ptr,
                                                     const int* __restrict__ rank,
                                                     int2* __restrict__ sedge) {
    int e = blockIdx.x * BS + threadIdx.x;
    if (e < E) {
        int d = ei[E + e];
        int p = row_ptr[d] + rank[e];
        sedge[p] = make_int2(ei[e], d);
    }
}

// ---------------- per-node U/V precompute ----------------
// Layer 1: feat=[pos_s, pos_s-pos_d] (6->32):
//   U[s] = pos_s @ (Wa[0:3]+Wa[3:6]) + ba ; V[d] = pos_d @ Wa[3:6]
__global__ __launch_bounds__(BS) void prep1_kernel(const float* __restrict__ pos,
                                                   const float* __restrict__ Wa,
                                                   const float* __restrict__ ba,
                                                   float* __restrict__ U, float* __restrict__ V,
                                                   int N) {
    int n = blockIdx.x * BS + threadIdx.x;
    if (n >= N) return;
    const float p[3] = {pos[3 * n], pos[3 * n + 1], pos[3 * n + 2]};
    v2f u[16], v[16];
#pragma unroll
    for (int g = 0; g < 16; ++g) {
        u[g] = *reinterpret_cast<const v2f*>(&ba[g * 2]);
        v2f z = {0.0f, 0.0f};
        v[g] = z;
    }
#pragma unroll
    for (int i = 0; i < 3; ++i) {
        const v2f f = {p[i], p[i]};
#pragma unroll
        for (int g = 0; g < 16; ++g) {
            const v2f wA = *reinterpret_cast<const v2f*>(&Wa[i * 32 + g * 2]);
            const v2f wB = *reinterpret_cast<const v2f*>(&Wa[(i + 3) * 32 + g * 2]);
            u[g] = __builtin_elementwise_fma(f, wA + wB, u[g]);
            v[g] = __builtin_elementwise_fma(f, wB, v[g]);
        }
    }
    float4* Up = reinterpret_cast<float4*>(U + (size_t)n * 32);
    float4* Vp = reinterpret_cast<float4*>(V + (size_t)n * 32);
#pragma unroll
    for (int q = 0; q < 8; ++q) {
        Up[q] = make_float4(u[2 * q].x, u[2 * q].y, u[2 * q + 1].x, u[2 * q + 1].y);
        Vp[q] = make_float4(v[2 * q].x, v[2 * q].y, v[2 * q + 1].x, v[2 * q + 1].y);
    }
}

// Layer 2: feat=[h_s (32), pos_s-pos_d] (35->32):
//   U[s] = h_s @ Wa[0:32] + pos_s @ Wa[32:35] + ba ; V[d] = pos_d @ Wa[32:35]
__global__ __launch_bounds__(BS) void prep2_kernel(const float* __restrict__ pos,
                                                   const float* __restrict__ h1,
                                                   const float* __restrict__ Wa,
                                                   const float* __restrict__ ba,
                                                   float* __restrict__ U, float* __restrict__ V,
                                                   int N) {
    int n = blockIdx.x * BS + threadIdx.x;
    if (n >= N) return;
    float h[32];
    const float4* hp = reinterpret_cast<const float4*>(h1 + (size_t)n * 32);
#pragma unroll
    for (int q = 0; q < 8; ++q) {
        float4 t = hp[q];
        h[4 * q] = t.x;
        h[4 * q + 1] = t.y;
        h[4 * q + 2] = t.z;
        h[4 * q + 3] = t.w;
    }
    const float p[3] = {pos[3 * n], pos[3 * n + 1], pos[3 * n + 2]};
    v2f u[16], v[16];
#pragma unroll
    for (int g = 0; g < 16; ++g) {
        u[g] = *reinterpret_cast<const v2f*>(&ba[g * 2]);
        v2f z = {0.0f, 0.0f};
        v[g] = z;
    }
#pragma unroll
    for (int i = 0; i < 32; ++i) {
        const v2f f = {h[i], h[i]};
#pragma unroll
        for (int g = 0; g < 16; ++g) {
            const v2f w = *reinterpret_cast<const v2f*>(&Wa[i * 32 + g * 2]);
            u[g] = __builtin_elementwise_fma(f, w, u[g]);
        }
    }
#pragma unroll
    for (int i = 0; i < 3; ++i) {
        const v2f f = {p[i], p[i]};
#pragma unroll
        for (int g = 0; g < 16; ++g) {
            const v2f w = *reinterpret_cast<const v2f*>(&Wa[(32 + i) * 32 + g * 2]);
            u[g] = __builtin_elementwise_fma(f, w, u[g]);
            v[g] = __builtin_elementwise_fma(f, w, v[g]);
        }
    }
    float4* Up = reinterpret_cast<float4*>(U + (size_t)n * 32);
    float4* Vp = reinterpret_cast<float4*>(V + (size_t)n * 32);
#pragma unroll
    for (int q = 0; q < 8; ++q) {
        Up[q] = make_float4(u[2 * q].x, u[2 * q].y, u[2 * q + 1].x, u[2 * q + 1].y);
        Vp[q] = make_float4(v[2 * q].x, v[2 * q].y, v[2 * q + 1].x, v[2 * q + 1].y);
    }
}

// ---------------- fused edge kernel (both layers identical now) ----------------
// hidden = relu(U[src] - V[dst]); m = hidden @ Wb + bb; block-segmented max.

__global__ __launch_bounds__(BS, 4) void edge_seg_kernel(
    const float4* __restrict__ U, const float4* __restrict__ V,
    const int* __restrict__ row_ptr, const int* __restrict__ cnt,
    const int2* __restrict__ sedge, const float* __restrict__ Wb,
    const float* __restrict__ bb, unsigned* __restrict__ agg, int E) {
    __shared__ float sm[BS][33];  // [edge-slot][channel], +1 pad

    const int tid = threadIdx.x;
    const int k0 = blockIdx.x * BS;
    const int blockEnd = min(k0 + BS, E);
    const int k = min(k0 + tid, E - 1);  // clamp, no divergence

    const int2 ed = sedge[k];
    const float4* Up = U + (size_t)ed.x * 8;
    const float4* Vp = V + (size_t)ed.y * 8;

    float hid[32];
#pragma unroll
    for (int q = 0; q < 8; ++q) {
        const float4 a = Up[q];
        const float4 b = Vp[q];
        hid[4 * q + 0] = fmaxf(a.x - b.x, 0.0f);
        hid[4 * q + 1] = fmaxf(a.y - b.y, 0.0f);
        hid[4 * q + 2] = fmaxf(a.z - b.z, 0.0f);
        hid[4 * q + 3] = fmaxf(a.w - b.w, 0.0f);
    }

    // m = hidden @ Wb + bb : h-outer, 16 live v2f accumulators, scalar-pipe W
    v2f acc[16];
#pragma unroll
    for (int g = 0; g < 16; ++g) acc[g] = *reinterpret_cast<const v2f*>(&bb[g * 2]);
#pragma unroll
    for (int h = 0; h < 32; ++h) {
        const v2f f = {hid[h], hid[h]};
#pragma unroll
        for (int g = 0; g < 16; ++g) {
            const v2f w = *reinterpret_cast<const v2f*>(&Wb[h * 32 + g * 2]);
            acc[g] = __builtin_elementwise_fma(f, w, acc[g]);
        }
    }
#pragma unroll
    for (int g = 0; g < 8; ++g) {
        *reinterpret_cast<float4*>(&sm[tid][g * 4]) =
            make_float4(acc[2 * g].x, acc[2 * g].y, acc[2 * g + 1].x, acc[2 * g + 1].y);
    }
    __syncthreads();

    // phase 2: segmented max over nodes covered by this block (4-wide ILP)
    const int d0 = sedge[k0].y;
    const int d1 = sedge[blockEnd - 1].y;
    const int nPairs = (d1 - d0 + 1) * 32;
    for (int idx = tid; idx < nPairs; idx += BS) {
        const int c = idx & 31;
        const int n = d0 + (idx >> 5);
        const int rs = row_ptr[n];
        const int re = rs + cnt[n];
        const int s0 = max(rs, k0);
        const int s1 = min(re, blockEnd);
        if (s0 >= s1) continue;
        float v0 = -INFINITY, v1 = -INFINITY, v2 = -INFINITY, v3 = -INFINITY;
        int e = s0;
        for (; e + 4 <= s1; e += 4) {
            float a0 = sm[e - k0 + 0][c];
            float a1 = sm[e - k0 + 1][c];
            float a2 = sm[e - k0 + 2][c];
            float a3 = sm[e - k0 + 3][c];
            v0 = fmaxf(v0, a0);
            v1 = fmaxf(v1, a1);
            v2 = fmaxf(v2, a2);
            v3 = fmaxf(v3, a3);
        }
        for (; e < s1; ++e) v0 = fmaxf(v0, sm[e - k0][c]);
        const float v = fmaxf(fmaxf(v0, v1), fmaxf(v2, v3));
        unsigned* p = &agg[(size_t)n * 32 + c];
        const unsigned enc = ordenc(v);
        if (rs >= k0 && re <= blockEnd)
            *p = enc;  // node fully inside this block
        else
            atomicMax(p, enc);  // straddles block boundary
    }
}

extern "C" void kernel_launch(void* const* d_in, const int* in_sizes, int n_in,
                              void* d_out, int out_size, void* d_ws, size_t ws_size,
                              hipStream_t stream) {
    const float* pos = (const float*)d_in[0];
    const int* ei = (const int*)d_in[1];
    const float* W1 = (const float*)d_in[3];
    const float* b1 = (const float*)d_in[4];
    const float* W2 = (const float*)d_in[5];
    const float* b2 = (const float*)d_in[6];
    const float* W3 = (const float*)d_in[7];
    const float* b3 = (const float*)d_in[8];
    const float* W4 = (const float*)d_in[9];
    const float* b4 = (const float*)d_in[10];

    const int E = in_sizes[1] / 2;
    const int N = in_sizes[0] / 3;
    const int n32 = N * 32;
    const int E4 = ((E + 3) / 4) * 4;
    const int NPAD = ((N + BS - 1) / BS) * BS;
    const int NB = (N + BS - 1) / BS;  // <= 512
    const int EB = (E + BS - 1) / BS;

    int* cnt = (int*)d_ws;             // NPAD ints
    int* row_ptr = cnt + NPAD;         // NPAD
    int* bsum = row_ptr + NPAD;        // 512
    int* bpre = bsum + 512;            // 512
    int2* sedge = (int2*)(bpre + 512); // E4 (8B each; offset mult of 4 ints)
    unsigned* aggA = (unsigned*)(sedge + E4);  // n32: layer-1 agg -> h1 (in place)
    float* Ubuf = (float*)(aggA + n32);        // n32 floats (reused by both layers)
    float* Vbuf = Ubuf + n32;                  // n32 floats
    int* rank = (int*)Ubuf;  // E4 ints, aliases Ubuf (dead before prep1 writes U)
    unsigned* aggB = (unsigned*)d_out;         // layer-2 agg -> final output

    const int gridN32 = (n32 + BS - 1) / BS;

    // CSR build (shared by both layers)
    init_kernel<<<gridN32, BS, 0, stream>>>(cnt, N, aggA, aggB, n32);
    hist_rank_kernel<<<EB, BS, 0, stream>>>(ei, E, cnt, rank);
    bsum_kernel<<<NB, BS, 0, stream>>>(cnt, N, bsum);
    bscan_kernel<<<1, 512, 0, stream>>>(bsum, NB, bpre);
    scan_kernel<<<NB, BS, 0, stream>>>(cnt, N, bpre, row_ptr);
    scatter_kernel<<<EB, BS, 0, stream>>>(ei, E, row_ptr, rank, sedge);

    // layer 1
    prep1_kernel<<<NB, BS, 0, stream>>>(pos, W1, b1, Ubuf, Vbuf, N);
    edge_seg_kernel<<<EB, BS, 0, stream>>>((const float4*)Ubuf, (const float4*)Vbuf, row_ptr,
                                           cnt, sedge, W2, b2, aggA, E);
    finalize_kernel<<<gridN32, BS, 0, stream>>>(aggA, n32);  // -> h1 floats

    // layer 2
    prep2_kernel<<<NB, BS, 0, stream>>>(pos, (const float*)aggA, W3, b3, Ubuf, Vbuf, N);
    edge_seg_kernel<<<EB, BS, 0, stream>>>((const float4*)Ubuf, (const float4*)Vbuf, row_ptr,
                                           cnt, sedge, W4, b4, aggB, E);
    finalize_kernel<<<gridN32, BS, 0, stream>>>(aggB, n32);
}

// Round 8
// 330.918 us; speedup vs baseline: 1.0701x; 1.0701x over previous
//
#include <hip/hip_runtime.h>
#include <stdint.h>

// PointNet EdgeConv, 2 layers. Round 8.
// R3: sorted CSR + block-segmented max in LDS.                 646 us
// R4: scalar-pipe weights, atomic-free sort.                   378 us
// R5: packed v_pk_fma_f32.                                     337 us
// R6: bf16 LDS squeeze. REGRESSED.                             345 us
// R7: algebraic MLP1 elimination (U[src]-V[dst]).              354 us (edges 2x68us)
// R8: MLP2 via v_mfma_f32_32x32x16_bf16 (4 MFMA/wave replaces 512 pk_fma/thd);
//     finalize-1 fused into prep2 (aggA decoded inline, h1 buffer gone).

#define BS 256

typedef float v2f __attribute__((ext_vector_type(2)));
typedef __attribute__((ext_vector_type(8))) short bf16x8;
typedef __attribute__((ext_vector_type(16))) float f32x16;

__device__ __forceinline__ unsigned ordenc(float f) {
    unsigned u = __float_as_uint(f);
    return (u & 0x80000000u) ? ~u : (u | 0x80000000u);
}
__device__ __forceinline__ float orddec(unsigned o) {
    unsigned u = (o & 0x80000000u) ? (o ^ 0x80000000u) : ~o;
    return __uint_as_float(u);
}
#define ORD_NEG_INF 0x007FFFFFu  // ordenc(-inf)

// pack two fp32 -> two bf16 (RNE): low half = x, high half = y
__device__ __forceinline__ unsigned pack_bf16_rne(float x, float y) {
    unsigned ux = __float_as_uint(x), uy = __float_as_uint(y);
    ux = ux + 0x7FFFu + ((ux >> 16) & 1u);
    uy = uy + 0x7FFFu + ((uy >> 16) & 1u);
    return (ux >> 16) | (uy & 0xFFFF0000u);
}

// ---------------- utility kernels ----------------

__global__ __launch_bounds__(BS) void init_kernel(int* __restrict__ cnt, int N,
                                                  unsigned* __restrict__ a,
                                                  unsigned* __restrict__ b, int n32) {
    int i = blockIdx.x * BS + threadIdx.x;
    if (i < N) cnt[i] = 0;
    if (i < n32) {
        a[i] = ORD_NEG_INF;
        b[i] = ORD_NEG_INF;
    }
}

__global__ __launch_bounds__(BS) void finalize_kernel(unsigned* __restrict__ buf, int n) {
    int i = blockIdx.x * BS + threadIdx.x;
    if (i < n) {
        float v = orddec(buf[i]);
        reinterpret_cast<float*>(buf)[i] = fmaxf(v, 0.0f);
    }
}

// ---------------- counting sort (CSR build) ----------------

__global__ __launch_bounds__(BS) void hist_rank_kernel(const int* __restrict__ ei, int E,
                                                       int* __restrict__ cnt,
                                                       int* __restrict__ rank) {
    int e = blockIdx.x * BS + threadIdx.x;
    if (e < E) rank[e] = atomicAdd(&cnt[ei[E + e]], 1);
}

__global__ __launch_bounds__(BS) void bsum_kernel(const int* __restrict__ cnt, int n,
                                                  int* __restrict__ bsum) {
    __shared__ int s[BS];
    int t = threadIdx.x;
    int i = blockIdx.x * BS + t;
    s[t] = (i < n) ? cnt[i] : 0;
    __syncthreads();
    for (int st = BS / 2; st > 0; st >>= 1) {
        if (t < st) s[t] += s[t + st];
        __syncthreads();
    }
    if (t == 0) bsum[blockIdx.x] = s[0];
}

__global__ __launch_bounds__(512) void bscan_kernel(const int* __restrict__ bsum, int nb,
                                                    int* __restrict__ bpre) {
    __shared__ int s[512];
    int t = threadIdx.x;
    int v = (t < nb) ? bsum[t] : 0;
    s[t] = v;
    __syncthreads();
    for (int off = 1; off < 512; off <<= 1) {
        int add = (t >= off) ? s[t - off] : 0;
        __syncthreads();
        s[t] += add;
        __syncthreads();
    }
    if (t < nb) bpre[t] = s[t] - v;  // exclusive
}

__global__ __launch_bounds__(BS) void scan_kernel(const int* __restrict__ cnt, int n,
                                                  const int* __restrict__ bpre,
                                                  int* __restrict__ row_ptr) {
    __shared__ int s[BS];
    int t = threadIdx.x;
    int i = blockIdx.x * BS + t;
    int v = (i < n) ? cnt[i] : 0;
    s[t] = v;
    __syncthreads();
    for (int off = 1; off < BS; off <<= 1) {
        int add = (t >= off) ? s[t - off] : 0;
        __syncthreads();
        s[t] += add;
        __syncthreads();
    }
    if (i < n) row_ptr[i] = bpre[blockIdx.x] + s[t] - v;
}

__global__ __launch_bounds__(BS) void scatter_kernel(const int* __restrict__ ei, int E,
                                                     const int* __restrict__ row_ptr,
                                                     const int* __restrict__ rank,
                                                     int2* __restrict__ sedge) {
    int e = blockIdx.x * BS + threadIdx.x;
    if (e < E) {
        int d = ei[E + e];
        int p = row_ptr[d] + rank[e];
        sedge[p] = make_int2(ei[e], d);
    }
}

// ---------------- per-node U/V precompute ----------------
// Layer 1: U[s] = pos_s @ (Wa[0:3]+Wa[3:6]) + ba ; V[d] = pos_d @ Wa[3:6]
__global__ __launch_bounds__(BS) void prep1_kernel(const float* __restrict__ pos,
                                                   const float* __restrict__ Wa,
                                                   const float* __restrict__ ba,
                                                   float* __restrict__ U, float* __restrict__ V,
                                                   int N) {
    int n = blockIdx.x * BS + threadIdx.x;
    if (n >= N) return;
    const float p[3] = {pos[3 * n], pos[3 * n + 1], pos[3 * n + 2]};
    v2f u[16], v[16];
#pragma unroll
    for (int g = 0; g < 16; ++g) {
        u[g] = *reinterpret_cast<const v2f*>(&ba[g * 2]);
        v2f z = {0.0f, 0.0f};
        v[g] = z;
    }
#pragma unroll
    for (int i = 0; i < 3; ++i) {
        const v2f f = {p[i], p[i]};
#pragma unroll
        for (int g = 0; g < 16; ++g) {
            const v2f wA = *reinterpret_cast<const v2f*>(&Wa[i * 32 + g * 2]);
            const v2f wB = *reinterpret_cast<const v2f*>(&Wa[(i + 3) * 32 + g * 2]);
            u[g] = __builtin_elementwise_fma(f, wA + wB, u[g]);
            v[g] = __builtin_elementwise_fma(f, wB, v[g]);
        }
    }
    float4* Up = reinterpret_cast<float4*>(U + (size_t)n * 32);
    float4* Vp = reinterpret_cast<float4*>(V + (size_t)n * 32);
#pragma unroll
    for (int q = 0; q < 8; ++q) {
        Up[q] = make_float4(u[2 * q].x, u[2 * q].y, u[2 * q + 1].x, u[2 * q + 1].y);
        Vp[q] = make_float4(v[2 * q].x, v[2 * q].y, v[2 * q + 1].x, v[2 * q + 1].y);
    }
}

// Layer 2: reads layer-1 agg (ordered uint), decodes h = relu(max) inline.
//   U[s] = h_s @ Wa[0:32] + pos_s @ Wa[32:35] + ba ; V[d] = pos_d @ Wa[32:35]
__global__ __launch_bounds__(BS) void prep2_kernel(const float* __restrict__ pos,
                                                   const unsigned* __restrict__ aggA,
                                                   const float* __restrict__ Wa,
                                                   const float* __restrict__ ba,
                                                   float* __restrict__ U, float* __restrict__ V,
                                                   int N) {
    int n = blockIdx.x * BS + threadIdx.x;
    if (n >= N) return;
    float h[32];
    const uint4* hp = reinterpret_cast<const uint4*>(aggA + (size_t)n * 32);
#pragma unroll
    for (int q = 0; q < 8; ++q) {
        uint4 t = hp[q];
        h[4 * q + 0] = fmaxf(orddec(t.x), 0.0f);
        h[4 * q + 1] = fmaxf(orddec(t.y), 0.0f);
        h[4 * q + 2] = fmaxf(orddec(t.z), 0.0f);
        h[4 * q + 3] = fmaxf(orddec(t.w), 0.0f);
    }
    const float p[3] = {pos[3 * n], pos[3 * n + 1], pos[3 * n + 2]};
    v2f u[16], v[16];
#pragma unroll
    for (int g = 0; g < 16; ++g) {
        u[g] = *reinterpret_cast<const v2f*>(&ba[g * 2]);
        v2f z = {0.0f, 0.0f};
        v[g] = z;
    }
#pragma unroll
    for (int i = 0; i < 32; ++i) {
        const v2f f = {h[i], h[i]};
#pragma unroll
        for (int g = 0; g < 16; ++g) {
            const v2f w = *reinterpret_cast<const v2f*>(&Wa[i * 32 + g * 2]);
            u[g] = __builtin_elementwise_fma(f, w, u[g]);
        }
    }
#pragma unroll
    for (int i = 0; i < 3; ++i) {
        const v2f f = {p[i], p[i]};
#pragma unroll
        for (int g = 0; g < 16; ++g) {
            const v2f w = *reinterpret_cast<const v2f*>(&Wa[(32 + i) * 32 + g * 2]);
            u[g] = __builtin_elementwise_fma(f, w, u[g]);
            v[g] = __builtin_elementwise_fma(f, w, v[g]);
        }
    }
    float4* Up = reinterpret_cast<float4*>(U + (size_t)n * 32);
    float4* Vp = reinterpret_cast<float4*>(V + (size_t)n * 32);
#pragma unroll
    for (int q = 0; q < 8; ++q) {
        Up[q] = make_float4(u[2 * q].x, u[2 * q].y, u[2 * q + 1].x, u[2 * q + 1].y);
        Vp[q] = make_float4(v[2 * q].x, v[2 * q].y, v[2 * q + 1].x, v[2 * q + 1].y);
    }
}

// ---------------- fused edge kernel: hid -> MFMA MLP2 -> segmented max ------
// LDS union (33792 B):
//   phase A: dwords [0, 5120)   = hid packed bf16 pairs, [edge][20] (16 used)
//            dwords [5120,5632) = Wbt bf16 pairs, [n][16]
//   phase B: floats [0, 8448)   = m matrix, sm[edge*33 + n]
__global__ __launch_bounds__(BS, 4) void edge_seg_kernel(
    const float4* __restrict__ U, const float4* __restrict__ V,
    const int* __restrict__ row_ptr, const int* __restrict__ cnt,
    const int2* __restrict__ sedge, const float* __restrict__ Wb,
    const float* __restrict__ bb, unsigned* __restrict__ agg, int E) {
    __shared__ __align__(16) unsigned lds[8448];

    const int tid = threadIdx.x;
    const int k0 = blockIdx.x * BS;
    const int blockEnd = min(k0 + BS, E);
    const int k = min(k0 + tid, E - 1);

    // stage Wbt: bf16 pairs, Wbt[n][pair p] = {Wb[2p][n], Wb[2p+1][n]}
    {
        const int n = tid & 31;
        const int p = (tid >> 5) * 2;  // 0,2,..,14 -> covers pairs 0..15
        lds[5120 + n * 16 + p + 0] = pack_bf16_rne(Wb[(2 * p + 0) * 32 + n],
                                                   Wb[(2 * p + 1) * 32 + n]);
        lds[5120 + n * 16 + p + 1] = pack_bf16_rne(Wb[(2 * p + 2) * 32 + n],
                                                   Wb[(2 * p + 3) * 32 + n]);
    }

    // hid = relu(U[src] - V[dst]) -> packed bf16 pairs in LDS
    const int2 ed = sedge[k];
    {
        const float4* Up = U + (size_t)ed.x * 8;
        const float4* Vp = V + (size_t)ed.y * 8;
#pragma unroll
        for (int q = 0; q < 8; ++q) {
            const float4 a = Up[q];
            const float4 b = Vp[q];
            const float h0 = fmaxf(a.x - b.x, 0.0f);
            const float h1 = fmaxf(a.y - b.y, 0.0f);
            const float h2 = fmaxf(a.z - b.z, 0.0f);
            const float h3 = fmaxf(a.w - b.w, 0.0f);
            lds[tid * 20 + 2 * q + 0] = pack_bf16_rne(h0, h1);
            lds[tid * 20 + 2 * q + 1] = pack_bf16_rne(h2, h3);
        }
    }
    __syncthreads();

    // MFMA fragments. wave w handles edge tiles 2w, 2w+1 (32 edges each).
    const int l = tid & 63;
    const int w = tid >> 6;
    const int half = l >> 5;  // k-half: lane covers k = half*8 + j (j=0..7)
    const int ln = l & 31;
    const uint4* ldsv = reinterpret_cast<const uint4*>(lds);

    const int e0 = 64 * w + ln;       // tile 2w edge (A rows = edges)
    const int e1 = e0 + 32;           // tile 2w+1 edge
    const uint4 au00 = ldsv[e0 * 5 + half];          // A tile0, k 0..15
    const uint4 au01 = ldsv[e0 * 5 + half + 2];      // A tile0, k 16..31
    const uint4 au10 = ldsv[e1 * 5 + half];
    const uint4 au11 = ldsv[e1 * 5 + half + 2];
    const uint4 bu0 = ldsv[1280 + ln * 4 + half];    // B (Wbt), k 0..15
    const uint4 bu1 = ldsv[1280 + ln * 4 + half + 2];// B, k 16..31
    const float bbn = bb[ln];
    __syncthreads();  // all LDS reads done; safe to overwrite with m matrix

    f32x16 c0 = {};
    f32x16 c1 = {};
    c0 = __builtin_amdgcn_mfma_f32_32x32x16_bf16(__builtin_bit_cast(bf16x8, au00),
                                                 __builtin_bit_cast(bf16x8, bu0), c0, 0, 0, 0);
    c0 = __builtin_amdgcn_mfma_f32_32x32x16_bf16(__builtin_bit_cast(bf16x8, au01),
                                                 __builtin_bit_cast(bf16x8, bu1), c0, 0, 0, 0);
    c1 = __builtin_amdgcn_mfma_f32_32x32x16_bf16(__builtin_bit_cast(bf16x8, au10),
                                                 __builtin_bit_cast(bf16x8, bu0), c1, 0, 0, 0);
    c1 = __builtin_amdgcn_mfma_f32_32x32x16_bf16(__builtin_bit_cast(bf16x8, au11),
                                                 __builtin_bit_cast(bf16x8, bu1), c1, 0, 0, 0);

    // write m to LDS: C layout col(n)=lane&31, row(edge)=(r&3)+8*(r>>2)+4*half
    float* smf = reinterpret_cast<float*>(lds);
#pragma unroll
    for (int r = 0; r < 16; ++r) {
        const int er = 64 * w + (r & 3) + 8 * (r >> 2) + 4 * half;
        smf[er * 33 + ln] = c0[r] + bbn;
        smf[(er + 32) * 33 + ln] = c1[r] + bbn;
    }
    __syncthreads();

    // phase 2: segmented max over nodes covered by this block (4-wide ILP)
    const int d0 = sedge[k0].y;
    const int d1 = sedge[blockEnd - 1].y;
    const int nPairs = (d1 - d0 + 1) * 32;
    for (int idx = tid; idx < nPairs; idx += BS) {
        const int c = idx & 31;
        const int n = d0 + (idx >> 5);
        const int rs = row_ptr[n];
        const int re = rs + cnt[n];
        const int s0 = max(rs, k0);
        const int s1 = min(re, blockEnd);
        if (s0 >= s1) continue;
        float v0 = -INFINITY, v1 = -INFINITY, v2 = -INFINITY, v3 = -INFINITY;
        int e = s0;
        for (; e + 4 <= s1; e += 4) {
            float a0 = smf[(e - k0 + 0) * 33 + c];
            float a1 = smf[(e - k0 + 1) * 33 + c];
            float a2 = smf[(e - k0 + 2) * 33 + c];
            float a3 = smf[(e - k0 + 3) * 33 + c];
            v0 = fmaxf(v0, a0);
            v1 = fmaxf(v1, a1);
            v2 = fmaxf(v2, a2);
            v3 = fmaxf(v3, a3);
        }
        for (; e < s1; ++e) v0 = fmaxf(v0, smf[(e - k0) * 33 + c]);
        const float v = fmaxf(fmaxf(v0, v1), fmaxf(v2, v3));
        unsigned* p = &agg[(size_t)n * 32 + c];
        const unsigned enc = ordenc(v);
        if (rs >= k0 && re <= blockEnd)
            *p = enc;  // node fully inside this block
        else
            atomicMax(p, enc);  // straddles block boundary
    }
}

extern "C" void kernel_launch(void* const* d_in, const int* in_sizes, int n_in,
                              void* d_out, int out_size, void* d_ws, size_t ws_size,
                              hipStream_t stream) {
    const float* pos = (const float*)d_in[0];
    const int* ei = (const int*)d_in[1];
    const float* W1 = (const float*)d_in[3];
    const float* b1 = (const float*)d_in[4];
    const float* W2 = (const float*)d_in[5];
    const float* b2 = (const float*)d_in[6];
    const float* W3 = (const float*)d_in[7];
    const float* b3 = (const float*)d_in[8];
    const float* W4 = (const float*)d_in[9];
    const float* b4 = (const float*)d_in[10];

    const int E = in_sizes[1] / 2;
    const int N = in_sizes[0] / 3;
    const int n32 = N * 32;
    const int E4 = ((E + 3) / 4) * 4;
    const int NPAD = ((N + BS - 1) / BS) * BS;
    const int NB = (N + BS - 1) / BS;  // <= 512
    const int EB = (E + BS - 1) / BS;

    int* cnt = (int*)d_ws;              // NPAD ints
    int* row_ptr = cnt + NPAD;          // NPAD
    int* bsum = row_ptr + NPAD;         // 512
    int* bpre = bsum + 512;             // 512
    int2* sedge = (int2*)(bpre + 512);  // E4
    unsigned* aggA = (unsigned*)(sedge + E4);  // n32 (stays ord-encoded; prep2 decodes)
    float* Ubuf = (float*)(aggA + n32);        // n32
    float* Vbuf = Ubuf + n32;                  // n32
    int* rank = (int*)Ubuf;  // E4 ints alias Ubuf (dead before prep1 writes U)
    unsigned* aggB = (unsigned*)d_out;

    const int gridN32 = (n32 + BS - 1) / BS;

    // CSR build (shared by both layers)
    init_kernel<<<gridN32, BS, 0, stream>>>(cnt, N, aggA, aggB, n32);
    hist_rank_kernel<<<EB, BS, 0, stream>>>(ei, E, cnt, rank);
    bsum_kernel<<<NB, BS, 0, stream>>>(cnt, N, bsum);
    bscan_kernel<<<1, 512, 0, stream>>>(bsum, NB, bpre);
    scan_kernel<<<NB, BS, 0, stream>>>(cnt, N, bpre, row_ptr);
    scatter_kernel<<<EB, BS, 0, stream>>>(ei, E, row_ptr, rank, sedge);

    // layer 1
    prep1_kernel<<<NB, BS, 0, stream>>>(pos, W1, b1, Ubuf, Vbuf, N);
    edge_seg_kernel<<<EB, BS, 0, stream>>>((const float4*)Ubuf, (const float4*)Vbuf, row_ptr,
                                           cnt, sedge, W2, b2, aggA, E);
    // layer 2 (prep2 decodes aggA inline; no finalize-1 pass)
    prep2_kernel<<<NB, BS, 0, stream>>>(pos, aggA, W3, b3, Ubuf, Vbuf, N);
    edge_seg_kernel<<<EB, BS, 0, stream>>>((const float4*)Ubuf, (const float4*)Vbuf, row_ptr,
                                           cnt, sedge, W4, b4, aggB, E);
    finalize_kernel<<<gridN32, BS, 0, stream>>>(aggB, n32);
}